// Round 12
// baseline (1839.629 us; speedup 1.0000x reference)
//
#include <hip/hip_runtime.h>

typedef __attribute__((ext_vector_type(4))) float  f32x4;
typedef __attribute__((ext_vector_type(8))) __bf16 bf16x8;
typedef __attribute__((ext_vector_type(4))) __bf16 bf16x4;

// ---------------------------------------------------------------------------
// prep: weight packing + bias concat + CPB table + d_out zeroing, one launch.
//  - W2[((h*6+ft)*8+ks)*64 + l][j] = qw[(ks*32+(l>>4)*8+j)*768 + (h*96+ft*16+(l&15))]
//  - Wp[((h*2+ft)*8+ks)*64 + l][j] = pw[(ks*32+(l>>4)*8+j)*256 + (h*32+ft*16+(l&15))]
//  - bcat = concat(q_bias, 0, v_bias) fp32[768]
//  - cpbias[8][64][64] f32
//  - blocks >= 147 zero d_out (required: fused kernel accumulates atomically)
// ---------------------------------------------------------------------------
__global__ __launch_bounds__(256) void prep_kernel(
    const float* __restrict__ qw, const float* __restrict__ pw,
    const float* __restrict__ qb, const float* __restrict__ vb,
    const float* __restrict__ w1, const float* __restrict__ b1,
    const float* __restrict__ w2,
    __bf16* __restrict__ W2, __bf16* __restrict__ Wp,
    float* __restrict__ bcat, float* __restrict__ cpbias,
    float* __restrict__ outz)
{
  if (blockIdx.x >= 147) {
    // zero d_out: 16384 blocks x 256 thr x 64 B = 268435456 B exactly
    size_t idx = ((size_t)(blockIdx.x - 147) * 256 + threadIdx.x) * 16;
    f32x4 z4 = {0.f, 0.f, 0.f, 0.f};
    *(f32x4*)(outz + idx)      = z4;
    *(f32x4*)(outz + idx + 4)  = z4;
    *(f32x4*)(outz + idx + 8)  = z4;
    *(f32x4*)(outz + idx + 12) = z4;
    return;
  }
  if (blockIdx.x < 131) {
    int i = blockIdx.x * 256 + threadIdx.x;
    if (i < 24576) {                       // 8 heads * 6 ft * 8 ks * 64 lanes
      int h = i / 3072, rem = i - h * 3072;
      int ft = rem >> 9, rem2 = rem & 511;
      int ks = rem2 >> 6, l = rem2 & 63;
      int g = l >> 4, c = l & 15;
      int col = h * 96 + ft * 16 + c;
      bf16x8 v;
      #pragma unroll
      for (int j = 0; j < 8; ++j)
        v[j] = (__bf16)qw[(ks * 32 + g * 8 + j) * 768 + col];
      *(bf16x8*)(W2 + (size_t)i * 8) = v;
    } else if (i < 24576 + 8192) {         // 8 oc-groups * 2 ft * 8 ks * 64 lanes
      int j = i - 24576;
      int wv = j >> 10, rem = j & 1023;
      int ft = rem >> 9, rem2 = rem & 511;
      int ks = rem2 >> 6, l = rem2 & 63;
      int g = l >> 4, c = l & 15;
      int col = wv * 32 + ft * 16 + c;
      bf16x8 v;
      #pragma unroll
      for (int j8 = 0; j8 < 8; ++j8)
        v[j8] = (__bf16)pw[(ks * 32 + g * 8 + j8) * 256 + col];
      *(bf16x8*)(Wp + (size_t)j * 8) = v;
    } else if (i < 24576 + 8192 + 768) {
      int cdx = i - 24576 - 8192;
      bcat[cdx] = (cdx < 256) ? qb[cdx] : ((cdx < 512) ? 0.0f : vb[cdx - 512]);
    }
  } else {
    int pair = (blockIdx.x - 131) * 256 + threadIdx.x;   // 4096 pairs (l, m)
    int lq = pair >> 6, mk = pair & 63;
    float d0 = (float)((lq >> 3) - (mk >> 3));
    float d1 = (float)((lq & 7) - (mk & 7));
    float v0 = d0 * (8.0f / 7.0f);
    float v1 = d1 * (8.0f / 7.0f);
    float s0 = (v0 > 0.f) ? 1.f : ((v0 < 0.f) ? -1.f : 0.f);
    float s1 = (v1 > 0.f) ? 1.f : ((v1 < 0.f) ? -1.f : 0.f);
    float r0 = s0 * log2f(fabsf(v0) + 1.0f) * (1.0f / 3.0f);
    float r1 = s1 * log2f(fabsf(v1) + 1.0f) * (1.0f / 3.0f);
    float acc[8] = {0.f, 0.f, 0.f, 0.f, 0.f, 0.f, 0.f, 0.f};
    #pragma unroll 4
    for (int j = 0; j < 512; ++j) {
      float h = fmaxf(r0 * w1[j] + r1 * w1[512 + j] + b1[j], 0.0f);
      #pragma unroll
      for (int q = 0; q < 8; ++q) acc[q] += h * w2[j * 8 + q];
    }
    #pragma unroll
    for (int q = 0; q < 8; ++q) {
      float s = 16.0f / (1.0f + __expf(-acc[q]));
      cpbias[(q * 64 + lq) * 64 + mk] = s;
    }
  }
}

// ---------------------------------------------------------------------------
__device__ __forceinline__ int win_region(int tok, int wi, int wj) {
  int r = tok >> 3, cc = tok & 7;
  int rh = (wi == 15) ? ((r < 4) ? 1 : 2) : 0;
  int rw = (wj == 15) ? ((cc < 4) ? 1 : 2) : 0;
  return rh * 3 + rw;
}

// 2-ft, 2-subtile slice of the per-head qkv GEMM (wave = head-half):
// a[ft][ntl] += W(FT+ft) @ xs tokens (2hf+ntl)*16+c, K=256. 16 acc regs.
template <int FT>
__device__ __forceinline__ void qkv2(const __bf16* __restrict__ Wh,
                                     const __bf16* xs, int l, int g, int c,
                                     int hf, f32x4 (&a)[2][2])
{
  const f32x4 zz = {0.f, 0.f, 0.f, 0.f};
  #pragma unroll
  for (int ft = 0; ft < 2; ++ft)
    #pragma unroll
    for (int ntl = 0; ntl < 2; ++ntl) a[ft][ntl] = zz;
  #pragma unroll
  for (int ks = 0; ks < 8; ++ks) {
    bf16x8 w0 = *(const bf16x8*)(Wh + (size_t)(((FT + 0) * 8 + ks) * 64 + l) * 8);
    bf16x8 w1 = *(const bf16x8*)(Wh + (size_t)(((FT + 1) * 8 + ks) * 64 + l) * 8);
    #pragma unroll
    for (int ntl = 0; ntl < 2; ++ntl) {
      int phys = (ks * 4 + g) ^ (c & 7);
      bf16x8 xf = *(const bf16x8*)&xs[((2 * hf + ntl) * 16 + c) * 256 + phys * 8];
      a[0][ntl] = __builtin_amdgcn_mfma_f32_16x16x32_bf16(w0, xf, a[0][ntl], 0, 0, 0);
      a[1][ntl] = __builtin_amdgcn_mfma_f32_16x16x32_bf16(w1, xf, a[1][ntl], 0, 0, 0);
    }
  }
}

// ---------------------------------------------------------------------------
// Fully fused qkv + windowed cosine attention + K-split output projection.
// Block = (window, batch, head-group z): 512 threads = 8 waves,
// wave = (head 4z+hl, q-half hf). LDS = xs 32 + kst 18 + vstT 18 = 68 KB and
// launch_bounds(512,4) (128 total-reg class) -> TWO INDEPENDENT blocks/CU:
// co-resident blocks desync across barriers so one block's compute hides the
// other's load/barrier stalls (the m114 mechanism R9's lockstep waves lacked).
// proj is K-split: block z computes the partial sum over its 4 heads' O
// (K-slice 128z..128z+127, entirely in its own xs) and atomicAdd's f32 into
// d_out (exactly 2 commutative adds/element -> deterministic; bias on z=0;
// d_out pre-zeroed by prep). Block-index mapping puts the z-pair on the SAME
// XCD 8 dispatch slots apart -> co-resident, atomics resolve in local L2.
// K-permutation trick: slot (g,j) -> k = 16*(j>>2)+4g+(j&3) on both MFMA
// operands; QK fragments pack from accumulators, P-fragment is p[8kp..8kp+7].
// ---------------------------------------------------------------------------
__global__ __launch_bounds__(512, 4) void fused_kernel(
    const float* __restrict__ x, const __bf16* __restrict__ W2,
    const __bf16* __restrict__ Wp, const float* __restrict__ bcat,
    const float* __restrict__ scale, const float* __restrict__ cpb,
    const float* __restrict__ pb, float* __restrict__ outf)
{
  __shared__ __align__(16) __bf16 xs[64 * 256];       // 32 KB: x tile, then O
  __shared__ __align__(16) __bf16 kst[4][64 * 36];    // 18 KB Kn [tok][unit]
  __shared__ __align__(16) __bf16 vstT[4][32 * 72];   // 18 KB V^T [unit][tok]
  const f32x4 zz = {0.f, 0.f, 0.f, 0.f};

  int t = threadIdx.x;
  int wv = t >> 6, hl = wv >> 1, hf = wv & 1;
  int l = t & 63, g = l >> 4, c = l & 15;
  // z-pair (same window) maps to same XCD, 8 dispatch slots apart
  int bid = blockIdx.x;
  int z  = (bid >> 3) & 1;
  int wb = ((bid >> 4) << 3) | (bid & 7);   // 0..4095
  int win = wb & 255, b = wb >> 8;
  int h = 4 * z + hl;
  int wi = win >> 4, wj = win & 15;
  bool edge = (wi == 15) || (wj == 15);

  // ---- stage x tile (cyclic shift folded into source address) ----
  {
    int r = t >> 3;                      // token 0..63
    int q8 = t & 7;                      // 32-float chunk of 256 channels
    int ht = (wi * 8 + (r >> 3) + 4) & 127;
    int wt = (wj * 8 + (r & 7) + 4) & 127;
    const float* src = x + (size_t)((b * 128 + ht) * 128 + wt) * 256 + q8 * 32;
    #pragma unroll
    for (int q = 0; q < 4; ++q) {
      f32x4 a0 = *(const f32x4*)(src + q * 8);
      f32x4 a1 = *(const f32x4*)(src + q * 8 + 4);
      bf16x8 v;
      #pragma unroll
      for (int j = 0; j < 4; ++j) { v[j] = (__bf16)a0[j]; v[4 + j] = (__bf16)a1[j]; }
      int phys = (q8 * 4 + q) ^ (r & 7);
      *(bf16x8*)&xs[r * 256 + phys * 8] = v;
    }
  }
  __syncthreads();

  int toko[2];
  #pragma unroll
  for (int ntl = 0; ntl < 2; ++ntl) {
    int tok = (2 * hf + ntl) * 16 + c;
    int ht = (wi * 8 + (tok >> 3) + 4) & 127;
    int wt = (wj * 8 + (tok & 7) + 4) & 127;
    toko[ntl] = ((b * 128 + ht) * 128 + wt) * 256;
  }

  const __bf16* Wh = W2 + (size_t)h * 24576;
  float ls = __expf(fminf(scale[h], 4.6051701859880914f));  // ln(100)

  // ==== q pass (ft 0,1) -> qB (registers) ====
  bf16x8 qB[2];
  {
    f32x4 a[2][2];
    qkv2<0>(Wh, xs, l, g, c, hf, a);
    f32x4 b0 = *(const f32x4*)&bcat[h * 96 + 0  + 4 * g];
    f32x4 b1 = *(const f32x4*)&bcat[h * 96 + 16 + 4 * g];
    #pragma unroll
    for (int ntl = 0; ntl < 2; ++ntl) {
      a[0][ntl] += b0; a[1][ntl] += b1;
      float s = 0.f;
      #pragma unroll
      for (int i = 0; i < 4; ++i)
        s += a[0][ntl][i] * a[0][ntl][i] + a[1][ntl][i] * a[1][ntl][i];
      s += __shfl_xor(s, 16); s += __shfl_xor(s, 32);
      float r = rsqrtf(fmaxf(s, 1.55e-5f)) * ls;
      #pragma unroll
      for (int i = 0; i < 4; ++i) {
        qB[ntl][i]     = (__bf16)(a[0][ntl][i] * r);
        qB[ntl][4 + i] = (__bf16)(a[1][ntl][i] * r);
      }
    }
  }

  // ==== k pass (ft 2,3) -> kst (shared across the head's two waves) ====
  {
    f32x4 a[2][2];
    qkv2<2>(Wh, xs, l, g, c, hf, a);
    f32x4 b0 = *(const f32x4*)&bcat[h * 96 + 32 + 4 * g];
    f32x4 b1 = *(const f32x4*)&bcat[h * 96 + 48 + 4 * g];
    #pragma unroll
    for (int ntl = 0; ntl < 2; ++ntl) {
      a[0][ntl] += b0; a[1][ntl] += b1;
      float s = 0.f;
      #pragma unroll
      for (int i = 0; i < 4; ++i)
        s += a[0][ntl][i] * a[0][ntl][i] + a[1][ntl][i] * a[1][ntl][i];
      s += __shfl_xor(s, 16); s += __shfl_xor(s, 32);
      float r = rsqrtf(fmaxf(s, 1.55e-5f));
      bf16x4 k0, k1;
      #pragma unroll
      for (int i = 0; i < 4; ++i) {
        k0[i] = (__bf16)(a[0][ntl][i] * r);
        k1[i] = (__bf16)(a[1][ntl][i] * r);
      }
      int tok = (2 * hf + ntl) * 16 + c;
      *(bf16x4*)&kst[hl][tok * 36 + 4 * g]      = k0;
      *(bf16x4*)&kst[hl][tok * 36 + 16 + 4 * g] = k1;
    }
  }

  // ==== v pass (ft 4,5) -> vstT [unit][tok] ====
  {
    f32x4 a[2][2];
    qkv2<4>(Wh, xs, l, g, c, hf, a);
    f32x4 b0 = *(const f32x4*)&bcat[h * 96 + 64 + 4 * g];
    f32x4 b1 = *(const f32x4*)&bcat[h * 96 + 80 + 4 * g];
    #pragma unroll
    for (int ntl = 0; ntl < 2; ++ntl) {
      int tok = (2 * hf + ntl) * 16 + c;
      #pragma unroll
      for (int i = 0; i < 4; ++i) {
        vstT[hl][(4 * g + i) * 72 + tok]      = (__bf16)(a[0][ntl][i] + b0[i]);
        vstT[hl][(16 + 4 * g + i) * 72 + tok] = (__bf16)(a[1][ntl][i] + b1[i]);
      }
    }
  }
  __syncthreads();   // kst/vstT visible; all xs reads done (xs becomes O)

  // ---- K A-fragments: slot (g,j) -> unit = 16*(j>>2)+4g+(j&3), tok = 16mt+c
  bf16x8 kA[4];
  #pragma unroll
  for (int mt = 0; mt < 4; ++mt) {
    bf16x4 lo = *(const bf16x4*)&kst[hl][(mt * 16 + c) * 36 + 4 * g];
    bf16x4 hi = *(const bf16x4*)&kst[hl][(mt * 16 + c) * 36 + 16 + 4 * g];
    #pragma unroll
    for (int i = 0; i < 4; ++i) { kA[mt][i] = lo[i]; kA[mt][4 + i] = hi[i]; }
  }
  // ---- V^T A-fragments: unit = 16mh+c, tok slot (g,j) -> 32kp+16(j>>2)+4g+(j&3)
  bf16x8 va[2][2];   // [mh][kp]
  #pragma unroll
  for (int mh = 0; mh < 2; ++mh)
    #pragma unroll
    for (int kp = 0; kp < 2; ++kp) {
      bf16x4 lo = *(const bf16x4*)&vstT[hl][(16 * mh + c) * 72 + 32 * kp + 4 * g];
      bf16x4 hi = *(const bf16x4*)&vstT[hl][(16 * mh + c) * 72 + 32 * kp + 16 + 4 * g];
      #pragma unroll
      for (int i = 0; i < 4; ++i) { va[mh][kp][i] = lo[i]; va[mh][kp][4 + i] = hi[i]; }
    }

  // ==== QK^T + softmax + PV for this wave's 2 q-subtiles; O -> xs ====
  #pragma unroll
  for (int ntl = 0; ntl < 2; ++ntl) {
    f32x4 tt4[4];
    #pragma unroll
    for (int mt = 0; mt < 4; ++mt)
      tt4[mt] = __builtin_amdgcn_mfma_f32_16x16x32_bf16(kA[mt], qB[ntl], zz, 0, 0, 0);
    int q = (2 * hf + ntl) * 16 + c;
    float p[16];
    #pragma unroll
    for (int mt = 0; mt < 4; ++mt) {
      f32x4 bb = *(const f32x4*)&cpb[(h * 64 + q) * 64 + mt * 16 + 4 * g];
      #pragma unroll
      for (int i = 0; i < 4; ++i) p[mt * 4 + i] = tt4[mt][i] + bb[i];
    }
    if (edge) {
      int regq = win_region(q, wi, wj);
      #pragma unroll
      for (int mt = 0; mt < 4; ++mt)
        #pragma unroll
        for (int i = 0; i < 4; ++i) {
          int k = mt * 16 + 4 * g + i;
          if (win_region(k, wi, wj) != regq) p[mt * 4 + i] -= 100.0f;
        }
    }
    float mx = -1e30f;
    #pragma unroll
    for (int j = 0; j < 16; ++j) mx = fmaxf(mx, p[j]);
    mx = fmaxf(mx, __shfl_xor(mx, 16));
    mx = fmaxf(mx, __shfl_xor(mx, 32));
    float sum = 0.f;
    #pragma unroll
    for (int j = 0; j < 16; ++j) { p[j] = __expf(p[j] - mx); sum += p[j]; }
    sum += __shfl_xor(sum, 16); sum += __shfl_xor(sum, 32);
    float rinv = 1.0f / sum;
    bf16x8 pf0, pf1;
    #pragma unroll
    for (int j = 0; j < 8; ++j) { pf0[j] = (__bf16)p[j]; pf1[j] = (__bf16)p[8 + j]; }
    int tok = q;
    #pragma unroll
    for (int mh = 0; mh < 2; ++mh) {
      f32x4 oo = __builtin_amdgcn_mfma_f32_16x16x32_bf16(va[mh][0], pf0, zz, 0, 0, 0);
      oo = __builtin_amdgcn_mfma_f32_16x16x32_bf16(va[mh][1], pf1, oo, 0, 0, 0);
      int chunk = h * 4 + 2 * mh + (g >> 1);     // ch = h*32+16*mh+4*g -> /8
      int phys = chunk ^ (tok & 7);
      bf16x4 ov = { (__bf16)(oo[0] * rinv), (__bf16)(oo[1] * rinv),
                    (__bf16)(oo[2] * rinv), (__bf16)(oo[3] * rinv) };
      *(bf16x4*)&xs[tok * 256 + phys * 8 + 4 * (g & 1)] = ov;
    }
  }
  __syncthreads();   // all O writes visible

  // ==== K-split output projection: partial C[256 oc][32 tok] over this
  // block's K-slice (ks = 4z..4z+3); atomicAdd f32 into d_out ====
  #pragma unroll
  for (int s2 = 0; s2 < 2; ++s2) {
    int hp = hl + 4 * s2;                // output oc-group 0..7
    const __bf16* Wph = Wp + (size_t)hp * 8192;
    f32x4 acc2[2][2];
    #pragma unroll
    for (int ft = 0; ft < 2; ++ft)
      #pragma unroll
      for (int ntl = 0; ntl < 2; ++ntl) acc2[ft][ntl] = zz;
    #pragma unroll
    for (int ks4 = 0; ks4 < 4; ++ks4) {
      int ks = 4 * z + ks4;
      bf16x8 w0 = *(const bf16x8*)(Wph + (size_t)((0 * 8 + ks) * 64 + l) * 8);
      bf16x8 w1 = *(const bf16x8*)(Wph + (size_t)((1 * 8 + ks) * 64 + l) * 8);
      #pragma unroll
      for (int ntl = 0; ntl < 2; ++ntl) {
        int tok = (2 * hf + ntl) * 16 + c;
        int phys = (ks * 4 + g) ^ (c & 7);
        bf16x8 xf = *(const bf16x8*)&xs[tok * 256 + phys * 8];
        acc2[0][ntl] = __builtin_amdgcn_mfma_f32_16x16x32_bf16(w0, xf, acc2[0][ntl], 0, 0, 0);
        acc2[1][ntl] = __builtin_amdgcn_mfma_f32_16x16x32_bf16(w1, xf, acc2[1][ntl], 0, 0, 0);
      }
    }
    #pragma unroll
    for (int ft = 0; ft < 2; ++ft) {
      f32x4 bb = *(const f32x4*)&pb[hp * 32 + ft * 16 + 4 * g];
      #pragma unroll
      for (int ntl = 0; ntl < 2; ++ntl) {
        f32x4 val = acc2[ft][ntl];
        if (z == 0) val += bb;           // bias added exactly once
        float* dst = outf + toko[ntl] + hp * 32 + ft * 16 + 4 * g;
        #pragma unroll
        for (int i = 0; i < 4; ++i) atomicAdd(dst + i, val[i]);
      }
    }
  }
}

// ---------------------------------------------------------------------------
extern "C" void kernel_launch(void* const* d_in, const int* in_sizes, int n_in,
                              void* d_out, int out_size, void* d_ws, size_t ws_size,
                              hipStream_t stream)
{
  const float* x      = (const float*)d_in[0];
  const float* qkv_w  = (const float*)d_in[1];
  const float* q_bias = (const float*)d_in[2];
  const float* v_bias = (const float*)d_in[3];
  const float* scale  = (const float*)d_in[4];
  const float* cpb_w1 = (const float*)d_in[5];
  const float* cpb_b1 = (const float*)d_in[6];
  const float* cpb_w2 = (const float*)d_in[7];
  const float* proj_w = (const float*)d_in[8];
  const float* proj_b = (const float*)d_in[9];

  char* ws = (char*)d_ws;
  // layout (bytes):
  //   [0, 393216)         W2 bf16 packed qkv weights
  //   [393216, 524288)    Wp bf16 packed proj weights
  //   [524288, 527360)    bcat f32[768]
  //   [527360, 658432)    cpb bias f32 [8][64][64]
  __bf16* W2   = (__bf16*)(ws);
  __bf16* Wp   = (__bf16*)(ws + 393216LL);
  float*  bcat = (float*) (ws + 524288LL);
  float*  cpb  = (float*) (ws + 527360LL);

  prep_kernel<<<147 + 16384, 256, 0, stream>>>(qkv_w, proj_w, q_bias, v_bias,
                                               cpb_w1, cpb_b1, cpb_w2,
                                               W2, Wp, bcat, cpb, (float*)d_out);
  fused_kernel<<<8192, 512, 0, stream>>>(x, W2, Wp, bcat, scale, cpb,
                                         proj_b, (float*)d_out);
}

// Round 14
// 445.354 us; speedup vs baseline: 4.1307x; 4.1307x over previous
//
#include <hip/hip_runtime.h>

typedef __attribute__((ext_vector_type(4))) float  f32x4;
typedef __attribute__((ext_vector_type(8))) __bf16 bf16x8;
typedef __attribute__((ext_vector_type(4))) __bf16 bf16x4;

// ---------------------------------------------------------------------------
// prep: weight packing + bias concat + CPB table, one launch.
// Blocks [0,355): i = bid*256+tid covers
//   [0, 24576)              W2 packed qkv weights
//   [24576, 90112)          pT = proj_w^T [N=256][K=256] bf16
//   [90112, 90880)          bcat = concat(q_bias, 0, v_bias) f32[768]
// Blocks [355, 371): CPB table cpbias[8][64][64] f32 (4096 (l,m) pairs)
// ---------------------------------------------------------------------------
__global__ __launch_bounds__(256) void prep_kernel(
    const float* __restrict__ qw, const float* __restrict__ pw,
    const float* __restrict__ qb, const float* __restrict__ vb,
    const float* __restrict__ w1, const float* __restrict__ b1,
    const float* __restrict__ w2,
    __bf16* __restrict__ W2, __bf16* __restrict__ pT,
    float* __restrict__ bcat, float* __restrict__ cpbias)
{
  if (blockIdx.x < 355) {
    int i = blockIdx.x * 256 + threadIdx.x;
    if (i < 24576) {                       // 8 heads * 6 ft * 8 ks * 64 lanes
      int h = i / 3072, rem = i - h * 3072;
      int ft = rem >> 9, rem2 = rem & 511;
      int ks = rem2 >> 6, l = rem2 & 63;
      int g = l >> 4, c = l & 15;
      int col = h * 96 + ft * 16 + c;
      bf16x8 v;
      #pragma unroll
      for (int j = 0; j < 8; ++j)
        v[j] = (__bf16)qw[(ks * 32 + g * 8 + j) * 768 + col];
      *(bf16x8*)(W2 + (size_t)i * 8) = v;
    } else if (i < 24576 + 65536) {        // proj_w transpose [256][256]
      int j = i - 24576;
      int n = j >> 8, k = j & 255;
      pT[j] = (__bf16)pw[k * 256 + n];
    } else if (i < 24576 + 65536 + 768) {
      int cdx = i - 24576 - 65536;
      bcat[cdx] = (cdx < 256) ? qb[cdx] : ((cdx < 512) ? 0.0f : vb[cdx - 512]);
    }
  } else {
    int pair = (blockIdx.x - 355) * 256 + threadIdx.x;   // 4096 pairs (l, m)
    int lq = pair >> 6, mk = pair & 63;
    float d0 = (float)((lq >> 3) - (mk >> 3));
    float d1 = (float)((lq & 7) - (mk & 7));
    float v0 = d0 * (8.0f / 7.0f);
    float v1 = d1 * (8.0f / 7.0f);
    float s0 = (v0 > 0.f) ? 1.f : ((v0 < 0.f) ? -1.f : 0.f);
    float s1 = (v1 > 0.f) ? 1.f : ((v1 < 0.f) ? -1.f : 0.f);
    float r0 = s0 * log2f(fabsf(v0) + 1.0f) * (1.0f / 3.0f);
    float r1 = s1 * log2f(fabsf(v1) + 1.0f) * (1.0f / 3.0f);
    float acc[8] = {0.f, 0.f, 0.f, 0.f, 0.f, 0.f, 0.f, 0.f};
    #pragma unroll 4
    for (int j = 0; j < 512; ++j) {
      float h = fmaxf(r0 * w1[j] + r1 * w1[512 + j] + b1[j], 0.0f);
      #pragma unroll
      for (int q = 0; q < 8; ++q) acc[q] += h * w2[j * 8 + q];
    }
    #pragma unroll
    for (int q = 0; q < 8; ++q) {
      float s = 16.0f / (1.0f + __expf(-acc[q]));
      cpbias[(q * 64 + lq) * 64 + mk] = s;
    }
  }
}

// ---------------------------------------------------------------------------
__device__ __forceinline__ int win_region(int tok, int wi, int wj) {
  int r = tok >> 3, cc = tok & 7;
  int rh = (wi == 15) ? ((r < 4) ? 1 : 2) : 0;
  int rw = (wj == 15) ? ((cc < 4) ? 1 : 2) : 0;
  return rh * 3 + rw;
}

// 2-ft, 2-subtile slice of the per-head qkv GEMM (wave = head-half):
// a[ft][ntl] += W(FT+ft) @ xs tokens (2hf+ntl)*16+c, K=256. 16 acc regs.
template <int FT>
__device__ __forceinline__ void qkv2(const __bf16* __restrict__ Wh,
                                     const __bf16* xs, int l, int g, int c,
                                     int hf, f32x4 (&a)[2][2])
{
  const f32x4 zz = {0.f, 0.f, 0.f, 0.f};
  #pragma unroll
  for (int ft = 0; ft < 2; ++ft)
    #pragma unroll
    for (int ntl = 0; ntl < 2; ++ntl) a[ft][ntl] = zz;
  #pragma unroll
  for (int ks = 0; ks < 8; ++ks) {
    bf16x8 w0 = *(const bf16x8*)(Wh + (size_t)(((FT + 0) * 8 + ks) * 64 + l) * 8);
    bf16x8 w1 = *(const bf16x8*)(Wh + (size_t)(((FT + 1) * 8 + ks) * 64 + l) * 8);
    #pragma unroll
    for (int ntl = 0; ntl < 2; ++ntl) {
      int phys = (ks * 4 + g) ^ (c & 7);
      bf16x8 xf = *(const bf16x8*)&xs[((2 * hf + ntl) * 16 + c) * 256 + phys * 8];
      a[0][ntl] = __builtin_amdgcn_mfma_f32_16x16x32_bf16(w0, xf, a[0][ntl], 0, 0, 0);
      a[1][ntl] = __builtin_amdgcn_mfma_f32_16x16x32_bf16(w1, xf, a[1][ntl], 0, 0, 0);
    }
  }
}

// ---------------------------------------------------------------------------
// Fused qkv + windowed cosine attention (z-split). Block = (window, batch,
// head-group z): 512 threads = 8 waves, wave = (head 4z+hl, q-half hf).
// LDS = xs 32 + kst 18 + vstT 18 = 68 KB; launch_bounds(512,4) (128-total-reg
// class) -> TWO INDEPENDENT blocks/CU. Co-resident blocks desync across
// barriers so one block's compute hides the other's load/barrier stalls.
// O is written DIRECTLY to a bf16 workspace (block z owns channels
// 128z..128z+127 -> disjoint, no reduction, no atomics). z-pair maps to the
// same XCD 8 dispatch slots apart -> x tile fetched once from HBM, second
// block hits L2 (R12 measured FETCH = 134 MB = half of x).
// K-permutation trick: slot (g,j) -> k = 16*(j>>2)+4g+(j&3) on both MFMA
// operands; QK fragments pack from accumulators, P-fragment is p[8kp..8kp+7].
// ---------------------------------------------------------------------------
__global__ __launch_bounds__(512, 4) void fused_kernel(
    const float* __restrict__ x, const __bf16* __restrict__ W2,
    const float* __restrict__ bcat, const float* __restrict__ scale,
    const float* __restrict__ cpb, __bf16* __restrict__ aout)
{
  __shared__ __align__(16) __bf16 xs[64 * 256];       // 32 KB x tile
  __shared__ __align__(16) __bf16 kst[4][64 * 36];    // 18 KB Kn [tok][unit]
  __shared__ __align__(16) __bf16 vstT[4][32 * 72];   // 18 KB V^T [unit][tok]
  const f32x4 zz = {0.f, 0.f, 0.f, 0.f};

  int t = threadIdx.x;
  int wv = t >> 6, hl = wv >> 1, hf = wv & 1;
  int l = t & 63, g = l >> 4, c = l & 15;
  // z-pair (same window) maps to same XCD, 8 dispatch slots apart
  int bid = blockIdx.x;
  int z  = (bid >> 3) & 1;
  int wb = ((bid >> 4) << 3) | (bid & 7);   // 0..4095
  int win = wb & 255, b = wb >> 8;
  int h = 4 * z + hl;
  int wi = win >> 4, wj = win & 15;
  bool edge = (wi == 15) || (wj == 15);

  // ---- stage x tile (cyclic shift folded into source address) ----
  {
    int r = t >> 3;                      // token 0..63
    int q8 = t & 7;                      // 32-float chunk of 256 channels
    int ht = (wi * 8 + (r >> 3) + 4) & 127;
    int wt = (wj * 8 + (r & 7) + 4) & 127;
    const float* src = x + (size_t)((b * 128 + ht) * 128 + wt) * 256 + q8 * 32;
    #pragma unroll
    for (int q = 0; q < 4; ++q) {
      f32x4 a0 = *(const f32x4*)(src + q * 8);
      f32x4 a1 = *(const f32x4*)(src + q * 8 + 4);
      bf16x8 v;
      #pragma unroll
      for (int j = 0; j < 4; ++j) { v[j] = (__bf16)a0[j]; v[4 + j] = (__bf16)a1[j]; }
      int phys = (q8 * 4 + q) ^ (r & 7);
      *(bf16x8*)&xs[r * 256 + phys * 8] = v;
    }
  }
  __syncthreads();

  int toko[2];
  #pragma unroll
  for (int ntl = 0; ntl < 2; ++ntl) {
    int tok = (2 * hf + ntl) * 16 + c;
    int ht = (wi * 8 + (tok >> 3) + 4) & 127;
    int wt = (wj * 8 + (tok & 7) + 4) & 127;
    toko[ntl] = ((b * 128 + ht) * 128 + wt) * 256;
  }

  const __bf16* Wh = W2 + (size_t)h * 24576;
  float ls = __expf(fminf(scale[h], 4.6051701859880914f));  // ln(100)

  // ==== q pass (ft 0,1) -> qB (registers) ====
  bf16x8 qB[2];
  {
    f32x4 a[2][2];
    qkv2<0>(Wh, xs, l, g, c, hf, a);
    f32x4 b0 = *(const f32x4*)&bcat[h * 96 + 0  + 4 * g];
    f32x4 b1 = *(const f32x4*)&bcat[h * 96 + 16 + 4 * g];
    #pragma unroll
    for (int ntl = 0; ntl < 2; ++ntl) {
      a[0][ntl] += b0; a[1][ntl] += b1;
      float s = 0.f;
      #pragma unroll
      for (int i = 0; i < 4; ++i)
        s += a[0][ntl][i] * a[0][ntl][i] + a[1][ntl][i] * a[1][ntl][i];
      s += __shfl_xor(s, 16); s += __shfl_xor(s, 32);
      float r = rsqrtf(fmaxf(s, 1.55e-5f)) * ls;
      #pragma unroll
      for (int i = 0; i < 4; ++i) {
        qB[ntl][i]     = (__bf16)(a[0][ntl][i] * r);
        qB[ntl][4 + i] = (__bf16)(a[1][ntl][i] * r);
      }
    }
  }

  // ==== k pass (ft 2,3) -> kst (shared across the head's two waves) ====
  {
    f32x4 a[2][2];
    qkv2<2>(Wh, xs, l, g, c, hf, a);
    f32x4 b0 = *(const f32x4*)&bcat[h * 96 + 32 + 4 * g];
    f32x4 b1 = *(const f32x4*)&bcat[h * 96 + 48 + 4 * g];
    #pragma unroll
    for (int ntl = 0; ntl < 2; ++ntl) {
      a[0][ntl] += b0; a[1][ntl] += b1;
      float s = 0.f;
      #pragma unroll
      for (int i = 0; i < 4; ++i)
        s += a[0][ntl][i] * a[0][ntl][i] + a[1][ntl][i] * a[1][ntl][i];
      s += __shfl_xor(s, 16); s += __shfl_xor(s, 32);
      float r = rsqrtf(fmaxf(s, 1.55e-5f));
      bf16x4 k0, k1;
      #pragma unroll
      for (int i = 0; i < 4; ++i) {
        k0[i] = (__bf16)(a[0][ntl][i] * r);
        k1[i] = (__bf16)(a[1][ntl][i] * r);
      }
      int tok = (2 * hf + ntl) * 16 + c;
      *(bf16x4*)&kst[hl][tok * 36 + 4 * g]      = k0;
      *(bf16x4*)&kst[hl][tok * 36 + 16 + 4 * g] = k1;
    }
  }

  // ==== v pass (ft 4,5) -> vstT [unit][tok] ====
  {
    f32x4 a[2][2];
    qkv2<4>(Wh, xs, l, g, c, hf, a);
    f32x4 b0 = *(const f32x4*)&bcat[h * 96 + 64 + 4 * g];
    f32x4 b1 = *(const f32x4*)&bcat[h * 96 + 80 + 4 * g];
    #pragma unroll
    for (int ntl = 0; ntl < 2; ++ntl) {
      int tok = (2 * hf + ntl) * 16 + c;
      #pragma unroll
      for (int i = 0; i < 4; ++i) {
        vstT[hl][(4 * g + i) * 72 + tok]      = (__bf16)(a[0][ntl][i] + b0[i]);
        vstT[hl][(16 + 4 * g + i) * 72 + tok] = (__bf16)(a[1][ntl][i] + b1[i]);
      }
    }
  }
  __syncthreads();   // kst/vstT visible

  // ---- K A-fragments: slot (g,j) -> unit = 16*(j>>2)+4g+(j&3), tok = 16mt+c
  bf16x8 kA[4];
  #pragma unroll
  for (int mt = 0; mt < 4; ++mt) {
    bf16x4 lo = *(const bf16x4*)&kst[hl][(mt * 16 + c) * 36 + 4 * g];
    bf16x4 hi = *(const bf16x4*)&kst[hl][(mt * 16 + c) * 36 + 16 + 4 * g];
    #pragma unroll
    for (int i = 0; i < 4; ++i) { kA[mt][i] = lo[i]; kA[mt][4 + i] = hi[i]; }
  }
  // ---- V^T A-fragments: unit = 16mh+c, tok slot (g,j) -> 32kp+16(j>>2)+4g+(j&3)
  bf16x8 va[2][2];   // [mh][kp]
  #pragma unroll
  for (int mh = 0; mh < 2; ++mh)
    #pragma unroll
    for (int kp = 0; kp < 2; ++kp) {
      bf16x4 lo = *(const bf16x4*)&vstT[hl][(16 * mh + c) * 72 + 32 * kp + 4 * g];
      bf16x4 hi = *(const bf16x4*)&vstT[hl][(16 * mh + c) * 72 + 32 * kp + 16 + 4 * g];
      #pragma unroll
      for (int i = 0; i < 4; ++i) { va[mh][kp][i] = lo[i]; va[mh][kp][4 + i] = hi[i]; }
    }

  // ==== QK^T + softmax + PV; O (scaled) written directly to aout ====
  #pragma unroll
  for (int ntl = 0; ntl < 2; ++ntl) {
    f32x4 tt4[4];
    #pragma unroll
    for (int mt = 0; mt < 4; ++mt)
      tt4[mt] = __builtin_amdgcn_mfma_f32_16x16x32_bf16(kA[mt], qB[ntl], zz, 0, 0, 0);
    int q = (2 * hf + ntl) * 16 + c;
    float p[16];
    #pragma unroll
    for (int mt = 0; mt < 4; ++mt) {
      f32x4 bb = *(const f32x4*)&cpb[(h * 64 + q) * 64 + mt * 16 + 4 * g];
      #pragma unroll
      for (int i = 0; i < 4; ++i) p[mt * 4 + i] = tt4[mt][i] + bb[i];
    }
    if (edge) {
      int regq = win_region(q, wi, wj);
      #pragma unroll
      for (int mt = 0; mt < 4; ++mt)
        #pragma unroll
        for (int i = 0; i < 4; ++i) {
          int k = mt * 16 + 4 * g + i;
          if (win_region(k, wi, wj) != regq) p[mt * 4 + i] -= 100.0f;
        }
    }
    float mx = -1e30f;
    #pragma unroll
    for (int j = 0; j < 16; ++j) mx = fmaxf(mx, p[j]);
    mx = fmaxf(mx, __shfl_xor(mx, 16));
    mx = fmaxf(mx, __shfl_xor(mx, 32));
    float sum = 0.f;
    #pragma unroll
    for (int j = 0; j < 16; ++j) { p[j] = __expf(p[j] - mx); sum += p[j]; }
    sum += __shfl_xor(sum, 16); sum += __shfl_xor(sum, 32);
    float rinv = 1.0f / sum;
    bf16x8 pf0, pf1;
    #pragma unroll
    for (int j = 0; j < 8; ++j) { pf0[j] = (__bf16)p[j]; pf1[j] = (__bf16)p[8 + j]; }
    #pragma unroll
    for (int mh = 0; mh < 2; ++mh) {
      f32x4 oo = __builtin_amdgcn_mfma_f32_16x16x32_bf16(va[mh][0], pf0, zz, 0, 0, 0);
      oo = __builtin_amdgcn_mfma_f32_16x16x32_bf16(va[mh][1], pf1, oo, 0, 0, 0);
      bf16x4 ov = { (__bf16)(oo[0] * rinv), (__bf16)(oo[1] * rinv),
                    (__bf16)(oo[2] * rinv), (__bf16)(oo[3] * rinv) };
      *(bf16x4*)(aout + toko[ntl] + h * 32 + 16 * mh + 4 * g) = ov;
    }
  }
}

// ---------------------------------------------------------------------------
// proj GEMM: C[M,256] = A[M,256] @ pT[256,256]^T, fp32 out + proj_b.
// (R4's known-correct kernel: 128x128 tile, 4 waves, XCD swizzle.)
// ---------------------------------------------------------------------------
__global__ __launch_bounds__(256) void proj_kernel(
    const __bf16* __restrict__ A, const __bf16* __restrict__ BT,
    float* __restrict__ Cout, const float* __restrict__ pb)
{
  const int K = 256, N = 256, NB = 2;
  __shared__ __align__(16) __bf16 lA[128 * 64];
  __shared__ __align__(16) __bf16 lB[128 * 64];
  int t = threadIdx.x;
  int wv = t >> 6, l = t & 63;
  int g = l >> 4, c = l & 15;
  int wr = wv >> 1, wc = wv & 1;

  int cpx = gridDim.x >> 3;
  int lin = (blockIdx.x & 7) * cpx + (blockIdx.x >> 3);
  int mblk = lin / NB;
  int nblk = lin - mblk * NB;

  int srow = wv * 8 + (l >> 3);
  const __bf16* Ab = A + (size_t)mblk * 128 * K;
  const __bf16* Bb = BT + (size_t)nblk * 128 * K;

  f32x4 acc[4][4];
  #pragma unroll
  for (int i = 0; i < 4; ++i)
    #pragma unroll
    for (int j = 0; j < 4; ++j) acc[i][j] = (f32x4){0.f, 0.f, 0.f, 0.f};

  for (int kt = 0; kt < 4; ++kt) {
    bf16x8 ra[4], rb[4];
    #pragma unroll
    for (int p = 0; p < 4; ++p) {
      ra[p] = *(const bf16x8*)(Ab + (size_t)(p * 32 + srow) * K + kt * 64 + (l & 7) * 8);
      rb[p] = *(const bf16x8*)(Bb + (size_t)(p * 32 + srow) * K + kt * 64 + (l & 7) * 8);
    }
    __syncthreads();
    #pragma unroll
    for (int p = 0; p < 4; ++p) {
      int row = p * 32 + srow;
      int phys = (l & 7) ^ (row & 7);
      *(bf16x8*)&lA[row * 64 + phys * 8] = ra[p];
      *(bf16x8*)&lB[row * 64 + phys * 8] = rb[p];
    }
    __syncthreads();
    #pragma unroll
    for (int kk = 0; kk < 2; ++kk) {
      bf16x8 af[4], bfr[4];
      #pragma unroll
      for (int mt = 0; mt < 4; ++mt) {
        int row = wr * 64 + mt * 16 + c;
        int ch = ((kk << 2) | g) ^ (c & 7);
        af[mt] = *(const bf16x8*)&lA[row * 64 + ch * 8];
      }
      #pragma unroll
      for (int nt = 0; nt < 4; ++nt) {
        int row = wc * 64 + nt * 16 + c;
        int ch = ((kk << 2) | g) ^ (c & 7);
        bfr[nt] = *(const bf16x8*)&lB[row * 64 + ch * 8];
      }
      #pragma unroll
      for (int mt = 0; mt < 4; ++mt)
        #pragma unroll
        for (int nt = 0; nt < 4; ++nt)
          acc[mt][nt] = __builtin_amdgcn_mfma_f32_16x16x32_bf16(af[mt], bfr[nt], acc[mt][nt], 0, 0, 0);
    }
  }

  #pragma unroll
  for (int mt = 0; mt < 4; ++mt) {
    #pragma unroll
    for (int nt = 0; nt < 4; ++nt) {
      int row0 = mblk * 128 + wr * 64 + mt * 16 + 4 * g;
      int col  = nblk * 128 + wc * 64 + nt * 16 + c;
      float bias = pb[col];
      #pragma unroll
      for (int i = 0; i < 4; ++i)
        Cout[(size_t)(row0 + i) * N + col] = acc[mt][nt][i] + bias;
    }
  }
}

// ---------------------------------------------------------------------------
extern "C" void kernel_launch(void* const* d_in, const int* in_sizes, int n_in,
                              void* d_out, int out_size, void* d_ws, size_t ws_size,
                              hipStream_t stream)
{
  const float* x      = (const float*)d_in[0];
  const float* qkv_w  = (const float*)d_in[1];
  const float* q_bias = (const float*)d_in[2];
  const float* v_bias = (const float*)d_in[3];
  const float* scale  = (const float*)d_in[4];
  const float* cpb_w1 = (const float*)d_in[5];
  const float* cpb_b1 = (const float*)d_in[6];
  const float* cpb_w2 = (const float*)d_in[7];
  const float* proj_w = (const float*)d_in[8];
  const float* proj_b = (const float*)d_in[9];

  char* ws = (char*)d_ws;
  // layout (bytes):
  //   [0, 134217728)           attn-out bf16 [262144][256]
  //   [134217728, 134610944)   W2 bf16 packed qkv weights
  //   [134610944, 134742016)   proj_w^T bf16 [256][256]
  //   [134742016, 134745088)   bcat f32[768]
  //   [134745088, 134876160)   cpb bias f32 [8][64][64]
  __bf16* aout = (__bf16*)(ws);
  __bf16* W2   = (__bf16*)(ws + 134217728LL);
  __bf16* pT   = (__bf16*)(ws + 134610944LL);
  float*  bcat = (float*) (ws + 134742016LL);
  float*  cpb  = (float*) (ws + 134745088LL);

  prep_kernel<<<371, 256, 0, stream>>>(qkv_w, proj_w, q_bias, v_bias,
                                       cpb_w1, cpb_b1, cpb_w2, W2, pT, bcat, cpb);
  fused_kernel<<<8192, 512, 0, stream>>>(x, W2, bcat, scale, cpb, aout);
  proj_kernel<<<4096, 256, 0, stream>>>(aout, pT, (float*)d_out, proj_b);
}

// Round 15
// 399.948 us; speedup vs baseline: 4.5997x; 1.1135x over previous
//
#include <hip/hip_runtime.h>

typedef __attribute__((ext_vector_type(4))) float  f32x4;
typedef __attribute__((ext_vector_type(8))) __bf16 bf16x8;
typedef __attribute__((ext_vector_type(4))) __bf16 bf16x4;

// ---------------------------------------------------------------------------
// prep: weight packing + bias concat + CPB table, one launch (147 blocks).
// Blocks [0,131): i = bid*256+tid covers
//   [0, 24576)        W2 packed qkv weights (head, ft, ks, lane fragment order)
//   [24576, 32768)    Wp packed proj weights (oc-group, ft, ks, lane)
//   [32768, 33536)    bcat = concat(q_bias, 0, v_bias) f32[768]
// Blocks [131, 147): CPB table cpbias[8][64][64] f32 (4096 (l,m) pairs)
// ---------------------------------------------------------------------------
__global__ __launch_bounds__(256) void prep_kernel(
    const float* __restrict__ qw, const float* __restrict__ pw,
    const float* __restrict__ qb, const float* __restrict__ vb,
    const float* __restrict__ w1, const float* __restrict__ b1,
    const float* __restrict__ w2,
    __bf16* __restrict__ W2, __bf16* __restrict__ Wp,
    float* __restrict__ bcat, float* __restrict__ cpbias)
{
  if (blockIdx.x < 131) {
    int i = blockIdx.x * 256 + threadIdx.x;
    if (i < 24576) {                       // 8 heads * 6 ft * 8 ks * 64 lanes
      int h = i / 3072, rem = i - h * 3072;
      int ft = rem >> 9, rem2 = rem & 511;
      int ks = rem2 >> 6, l = rem2 & 63;
      int g = l >> 4, c = l & 15;
      int col = h * 96 + ft * 16 + c;
      bf16x8 v;
      #pragma unroll
      for (int j = 0; j < 8; ++j)
        v[j] = (__bf16)qw[(ks * 32 + g * 8 + j) * 768 + col];
      *(bf16x8*)(W2 + (size_t)i * 8) = v;
    } else if (i < 24576 + 8192) {         // 8 oc-groups * 2 ft * 8 ks * 64 lanes
      int j = i - 24576;
      int wv = j >> 10, rem = j & 1023;
      int ft = rem >> 9, rem2 = rem & 511;
      int ks = rem2 >> 6, l = rem2 & 63;
      int g = l >> 4, c = l & 15;
      int col = wv * 32 + ft * 16 + c;
      bf16x8 v;
      #pragma unroll
      for (int j8 = 0; j8 < 8; ++j8)
        v[j8] = (__bf16)pw[(ks * 32 + g * 8 + j8) * 256 + col];
      *(bf16x8*)(Wp + (size_t)j * 8) = v;
    } else if (i < 24576 + 8192 + 768) {
      int cdx = i - 24576 - 8192;
      bcat[cdx] = (cdx < 256) ? qb[cdx] : ((cdx < 512) ? 0.0f : vb[cdx - 512]);
    }
  } else {
    int pair = (blockIdx.x - 131) * 256 + threadIdx.x;   // 4096 pairs (l, m)
    int lq = pair >> 6, mk = pair & 63;
    float d0 = (float)((lq >> 3) - (mk >> 3));
    float d1 = (float)((lq & 7) - (mk & 7));
    float v0 = d0 * (8.0f / 7.0f);
    float v1 = d1 * (8.0f / 7.0f);
    float s0 = (v0 > 0.f) ? 1.f : ((v0 < 0.f) ? -1.f : 0.f);
    float s1 = (v1 > 0.f) ? 1.f : ((v1 < 0.f) ? -1.f : 0.f);
    float r0 = s0 * log2f(fabsf(v0) + 1.0f) * (1.0f / 3.0f);
    float r1 = s1 * log2f(fabsf(v1) + 1.0f) * (1.0f / 3.0f);
    float acc[8] = {0.f, 0.f, 0.f, 0.f, 0.f, 0.f, 0.f, 0.f};
    #pragma unroll 4
    for (int j = 0; j < 512; ++j) {
      float h = fmaxf(r0 * w1[j] + r1 * w1[512 + j] + b1[j], 0.0f);
      #pragma unroll
      for (int q = 0; q < 8; ++q) acc[q] += h * w2[j * 8 + q];
    }
    #pragma unroll
    for (int q = 0; q < 8; ++q) {
      float s = 16.0f / (1.0f + __expf(-acc[q]));
      cpbias[(q * 64 + lq) * 64 + mk] = s;
    }
  }
}

// ---------------------------------------------------------------------------
__device__ __forceinline__ int win_region(int tok, int wi, int wj) {
  int r = tok >> 3, cc = tok & 7;
  int rh = (wi == 15) ? ((r < 4) ? 1 : 2) : 0;
  int rw = (wj == 15) ? ((cc < 4) ? 1 : 2) : 0;
  return rh * 3 + rw;
}

// ---------------------------------------------------------------------------
// Fused qkv-projection + windowed cosine attention (R4's verbatim 267-µs
// kernel). Block = (window, batch), 512 threads = 8 waves, wave = head.
// Phase 1: stage shifted x tile (64x256) fp32->bf16 into LDS (chunk-XOR swizzle).
// Phase 2 (per wave): GEMM C[feat 96][tok 64] = W2(h) @ xs, K=256 (8 ksteps,
//   24 MFMA each). Bias add, l2-norm q/k in C-layout, stage q/k/v to LDS.
// Phase 3: QK^T via mfma(K,Q), +cpb bias, shift mask, softmax (in-lane 16 +
//   shfl 16/32), P^T -> LDS (aliases dead q/k stage). PV: O^T = V^T @ P^T.
// ---------------------------------------------------------------------------
__global__ __launch_bounds__(512, 2) void fused_kernel(
    const float* __restrict__ x, const __bf16* __restrict__ W2,
    const float* __restrict__ bcat, const float* __restrict__ scale,
    const float* __restrict__ cpb, __bf16* __restrict__ out)
{
  __shared__ __align__(16) __bf16 xs[64 * 256];      // 32 KB
  __shared__ __align__(16) __bf16 qkp[8][64 * 72];   // 72 KB q/k stage -> P
  __shared__ __align__(16) __bf16 vst[8][64 * 36];   // 36 KB V [tok][unit]
  const f32x4 zz = {0.f, 0.f, 0.f, 0.f};

  int t = threadIdx.x;
  int h = t >> 6, l = t & 63, g = l >> 4, c = l & 15;
  int win = blockIdx.x, b = blockIdx.y;
  int wi = win >> 4, wj = win & 15;
  bool edge = (wi == 15) || (wj == 15);

  // ---- stage x tile (cyclic shift folded into source address) ----
  {
    int r = t >> 3;                      // local token 0..63
    int q8 = t & 7;                      // 32-float chunk of the 256 channels
    int ht = (wi * 8 + (r >> 3) + 4) & 127;
    int wt = (wj * 8 + (r & 7) + 4) & 127;
    const float* src = x + (size_t)((b * 128 + ht) * 128 + wt) * 256 + q8 * 32;
    #pragma unroll
    for (int q = 0; q < 4; ++q) {
      f32x4 a0 = *(const f32x4*)(src + q * 8);
      f32x4 a1 = *(const f32x4*)(src + q * 8 + 4);
      bf16x8 v;
      #pragma unroll
      for (int j = 0; j < 4; ++j) { v[j] = (__bf16)a0[j]; v[4 + j] = (__bf16)a1[j]; }
      int phys = (q8 * 4 + q) ^ (r & 7);
      *(bf16x8*)&xs[r * 256 + phys * 8] = v;
    }
  }
  __syncthreads();

  int toko[4];
  #pragma unroll
  for (int i = 0; i < 4; ++i) {
    int tok = 16 * i + c;
    int ht = (wi * 8 + (tok >> 3) + 4) & 127;
    int wt = (wj * 8 + (tok & 7) + 4) & 127;
    toko[i] = ((b * 128 + ht) * 128 + wt) * 256;
  }

  // ---- per-head qkv GEMM: acc[ft][tt] = C[ft*16+4g..+3][tt*16+c] ----
  f32x4 acc[6][4];
  #pragma unroll
  for (int ft = 0; ft < 6; ++ft)
    #pragma unroll
    for (int tt = 0; tt < 4; ++tt) acc[ft][tt] = zz;

  const __bf16* Wh = W2 + (size_t)h * 24576;
  #pragma unroll
  for (int ks = 0; ks < 8; ++ks) {
    bf16x8 wf[6], xf[4];
    #pragma unroll
    for (int ft = 0; ft < 6; ++ft)
      wf[ft] = *(const bf16x8*)(Wh + (size_t)((ft * 8 + ks) * 64 + l) * 8);
    #pragma unroll
    for (int tt = 0; tt < 4; ++tt) {
      int phys = (ks * 4 + g) ^ (c & 7);
      xf[tt] = *(const bf16x8*)&xs[(tt * 16 + c) * 256 + phys * 8];
    }
    #pragma unroll
    for (int ft = 0; ft < 6; ++ft)
      #pragma unroll
      for (int tt = 0; tt < 4; ++tt)
        acc[ft][tt] = __builtin_amdgcn_mfma_f32_16x16x32_bf16(wf[ft], xf[tt], acc[ft][tt], 0, 0, 0);
  }

  // ---- bias add (concat layout, col = h*96 + ft*16 + 4g + i) ----
  #pragma unroll
  for (int ft = 0; ft < 6; ++ft) {
    f32x4 bb = *(const f32x4*)&bcat[h * 96 + ft * 16 + 4 * g];
    #pragma unroll
    for (int tt = 0; tt < 4; ++tt) acc[ft][tt] += bb;
  }

  float ls = __expf(fminf(scale[h], 4.6051701859880914f));  // ln(100)

  // ---- l2-normalize q (ft 0,1) and k (ft 2,3); stage q,k,v to LDS ----
  #pragma unroll
  for (int tt = 0; tt < 4; ++tt) {
    float sq = 0.f, sk = 0.f;
    #pragma unroll
    for (int i = 0; i < 4; ++i) {
      sq += acc[0][tt][i] * acc[0][tt][i] + acc[1][tt][i] * acc[1][tt][i];
      sk += acc[2][tt][i] * acc[2][tt][i] + acc[3][tt][i] * acc[3][tt][i];
    }
    sq += __shfl_xor(sq, 16); sq += __shfl_xor(sq, 32);
    sk += __shfl_xor(sk, 16); sk += __shfl_xor(sk, 32);
    float rq = rsqrtf(fmaxf(sq, 1.55e-5f)) * ls;
    float rk = rsqrtf(fmaxf(sk, 1.55e-5f));
    __bf16* row = &qkp[h][(tt * 16 + c) * 72];
    bf16x4 w0, w1, w2, w3, v0, v1;
    #pragma unroll
    for (int i = 0; i < 4; ++i) {
      w0[i] = (__bf16)(acc[0][tt][i] * rq);
      w1[i] = (__bf16)(acc[1][tt][i] * rq);
      w2[i] = (__bf16)(acc[2][tt][i] * rk);
      w3[i] = (__bf16)(acc[3][tt][i] * rk);
      v0[i] = (__bf16)acc[4][tt][i];
      v1[i] = (__bf16)acc[5][tt][i];
    }
    *(bf16x4*)&row[4 * g]      = w0;   // q units 4g..
    *(bf16x4*)&row[16 + 4 * g] = w1;   // q units 16+4g..
    *(bf16x4*)&row[32 + 4 * g] = w2;   // k units 4g..
    *(bf16x4*)&row[48 + 4 * g] = w3;   // k units 16+4g..
    __bf16* vrow = &vst[h][(tt * 16 + c) * 36];
    *(bf16x4*)&vrow[4 * g]      = v0;
    *(bf16x4*)&vrow[16 + 4 * g] = v1;
  }

  // ---- fetch Q/K MFMA fragments (wave-private LDS, compiler orders) ----
  bf16x8 kf[4], qf[4];
  #pragma unroll
  for (int i = 0; i < 4; ++i) {
    kf[i] = *(const bf16x8*)&qkp[h][(16 * i + c) * 72 + 32 + 8 * g];
    qf[i] = *(const bf16x8*)&qkp[h][(16 * i + c) * 72 + 8 * g];
  }

  // ---- QK^T + softmax; P^T overwrites the dead q/k stage ----
  float rsum[4];
  __bf16* Pw = &qkp[h][0];
  #pragma unroll
  for (int nt = 0; nt < 4; ++nt) {
    f32x4 tt4[4];
    #pragma unroll
    for (int mt = 0; mt < 4; ++mt)
      tt4[mt] = __builtin_amdgcn_mfma_f32_16x16x32_bf16(kf[mt], qf[nt], zz, 0, 0, 0);
    int q = nt * 16 + c;
    float p[16];
    #pragma unroll
    for (int mt = 0; mt < 4; ++mt) {
      f32x4 bb = *(const f32x4*)&cpb[(h * 64 + q) * 64 + mt * 16 + 4 * g];
      #pragma unroll
      for (int i = 0; i < 4; ++i) p[mt * 4 + i] = tt4[mt][i] + bb[i];
    }
    if (edge) {
      int regq = win_region(q, wi, wj);
      #pragma unroll
      for (int mt = 0; mt < 4; ++mt)
        #pragma unroll
        for (int i = 0; i < 4; ++i) {
          int k = mt * 16 + 4 * g + i;
          if (win_region(k, wi, wj) != regq) p[mt * 4 + i] -= 100.0f;
        }
    }
    float mx = -1e30f;
    #pragma unroll
    for (int j = 0; j < 16; ++j) mx = fmaxf(mx, p[j]);
    mx = fmaxf(mx, __shfl_xor(mx, 16));
    mx = fmaxf(mx, __shfl_xor(mx, 32));
    float sum = 0.f;
    #pragma unroll
    for (int j = 0; j < 16; ++j) { p[j] = __expf(p[j] - mx); sum += p[j]; }
    sum += __shfl_xor(sum, 16); sum += __shfl_xor(sum, 32);
    rsum[nt] = sum;
    #pragma unroll
    for (int mt = 0; mt < 4; ++mt) {
      bf16x4 px = { (__bf16)p[mt * 4 + 0], (__bf16)p[mt * 4 + 1],
                    (__bf16)p[mt * 4 + 2], (__bf16)p[mt * 4 + 3] };
      *(bf16x4*)&Pw[q * 72 + mt * 16 + 4 * g] = px;
    }
  }

  // ---- O^T = V^T @ P^T ----
  #pragma unroll
  for (int mh = 0; mh < 2; ++mh) {
    f32x4 oacc[4];
    #pragma unroll
    for (int nt = 0; nt < 4; ++nt) oacc[nt] = zz;
    #pragma unroll
    for (int ks = 0; ks < 2; ++ks) {
      bf16x8 va;
      #pragma unroll
      for (int j = 0; j < 8; ++j)
        va[j] = vst[h][(32 * ks + 8 * g + j) * 36 + 16 * mh + c];
      #pragma unroll
      for (int nt = 0; nt < 4; ++nt) {
        bf16x8 pfr = *(const bf16x8*)&Pw[(nt * 16 + c) * 72 + 32 * ks + 8 * g];
        oacc[nt] = __builtin_amdgcn_mfma_f32_16x16x32_bf16(va, pfr, oacc[nt], 0, 0, 0);
      }
    }
    #pragma unroll
    for (int nt = 0; nt < 4; ++nt) {
      float rinv = 1.0f / rsum[nt];
      bf16x4 ov = { (__bf16)(oacc[nt][0] * rinv), (__bf16)(oacc[nt][1] * rinv),
                    (__bf16)(oacc[nt][2] * rinv), (__bf16)(oacc[nt][3] * rinv) };
      *(bf16x4*)(out + toko[nt] + h * 32 + 16 * mh + 4 * g) = ov;
    }
  }
}

// ---------------------------------------------------------------------------
// proj2: A-stationary output projection. Block = 128 tokens, 512 threads =
// 8 waves, wave = 32-oc group. A tile (128x256 bf16 = 64 KB) staged in LDS
// once (single barrier); weights read from packed L2-resident Wp (same
// fragment pattern as the fused designs' proj phase); 128 MFMA/wave;
// f32x4 coalesced stores + proj_b. Memory-bound: 134 MB read + 268 MB write.
// ---------------------------------------------------------------------------
__global__ __launch_bounds__(512, 4) void proj2_kernel(
    const __bf16* __restrict__ A, const __bf16* __restrict__ Wp,
    const float* __restrict__ pb, float* __restrict__ outf)
{
  __shared__ __align__(16) __bf16 os[128 * 256];   // 64 KB
  const f32x4 zz = {0.f, 0.f, 0.f, 0.f};
  int t = threadIdx.x;
  int wv = t >> 6, l = t & 63, g = l >> 4, c = l & 15;
  int mblk = blockIdx.x;                 // 2048 blocks x 128 tokens

  // ---- stage A tile (chunk-XOR swizzle, rows keep low-3-bit identity) ----
  {
    int r = t >> 2;                      // row 0..127
    int q4 = t & 3;                      // quarter of the 256 channels
    const __bf16* src = A + (size_t)(mblk * 128 + r) * 256 + q4 * 64;
    #pragma unroll
    for (int q = 0; q < 8; ++q) {
      bf16x8 v = *(const bf16x8*)(src + q * 8);
      int phys = (q4 * 8 + q) ^ (r & 7);
      *(bf16x8*)&os[r * 256 + phys * 8] = v;
    }
  }
  __syncthreads();

  f32x4 acc[2][8];
  #pragma unroll
  for (int ft = 0; ft < 2; ++ft)
    #pragma unroll
    for (int tt = 0; tt < 8; ++tt) acc[ft][tt] = zz;

  const __bf16* Wph = Wp + (size_t)wv * 8192;
  #pragma unroll
  for (int ks = 0; ks < 8; ++ks) {
    bf16x8 w0 = *(const bf16x8*)(Wph + (size_t)((0 * 8 + ks) * 64 + l) * 8);
    bf16x8 w1 = *(const bf16x8*)(Wph + (size_t)((1 * 8 + ks) * 64 + l) * 8);
    #pragma unroll
    for (int tt = 0; tt < 8; ++tt) {
      int phys = (ks * 4 + g) ^ (c & 7);
      bf16x8 xf = *(const bf16x8*)&os[(tt * 16 + c) * 256 + phys * 8];
      acc[0][tt] = __builtin_amdgcn_mfma_f32_16x16x32_bf16(w0, xf, acc[0][tt], 0, 0, 0);
      acc[1][tt] = __builtin_amdgcn_mfma_f32_16x16x32_bf16(w1, xf, acc[1][tt], 0, 0, 0);
    }
  }

  #pragma unroll
  for (int ft = 0; ft < 2; ++ft) {
    f32x4 bb = *(const f32x4*)&pb[wv * 32 + ft * 16 + 4 * g];
    #pragma unroll
    for (int tt = 0; tt < 8; ++tt) {
      f32x4 res = acc[ft][tt] + bb;
      *(f32x4*)&outf[(size_t)(mblk * 128 + tt * 16 + c) * 256 + wv * 32 + ft * 16 + 4 * g] = res;
    }
  }
}

// ---------------------------------------------------------------------------
extern "C" void kernel_launch(void* const* d_in, const int* in_sizes, int n_in,
                              void* d_out, int out_size, void* d_ws, size_t ws_size,
                              hipStream_t stream)
{
  const float* x      = (const float*)d_in[0];
  const float* qkv_w  = (const float*)d_in[1];
  const float* q_bias = (const float*)d_in[2];
  const float* v_bias = (const float*)d_in[3];
  const float* scale  = (const float*)d_in[4];
  const float* cpb_w1 = (const float*)d_in[5];
  const float* cpb_b1 = (const float*)d_in[6];
  const float* cpb_w2 = (const float*)d_in[7];
  const float* proj_w = (const float*)d_in[8];
  const float* proj_b = (const float*)d_in[9];

  char* ws = (char*)d_ws;
  // layout (bytes):
  //   [0, 134217728)           attn-out bf16 [262144][256]
  //   [134217728, 134610944)   W2 bf16 packed qkv weights
  //   [134610944, 134742016)   Wp bf16 packed proj weights
  //   [134742016, 134745088)   bcat f32[768]
  //   [134745088, 134876160)   cpb bias f32 [8][64][64]
  __bf16* aout = (__bf16*)(ws);
  __bf16* W2   = (__bf16*)(ws + 134217728LL);
  __bf16* Wp   = (__bf16*)(ws + 134610944LL);
  float*  bcat = (float*) (ws + 134742016LL);
  float*  cpb  = (float*) (ws + 134745088LL);

  prep_kernel<<<147, 256, 0, stream>>>(qkv_w, proj_w, q_bias, v_bias,
                                       cpb_w1, cpb_b1, cpb_w2, W2, Wp, bcat, cpb);
  fused_kernel<<<dim3(256, 16), 512, 0, stream>>>(x, W2, bcat, scale, cpb, aout);
  proj2_kernel<<<2048, 512, 0, stream>>>(aout, Wp, proj_b, (float*)d_out);
}